// Round 22
// baseline (260.936 us; speedup 1.0000x reference)
//
#include <hip/hip_runtime.h>
#include <hip/hip_bf16.h>
#include <stdint.h>

typedef __bf16 bf16;
typedef __bf16 bf16x8 __attribute__((ext_vector_type(8)));
typedef __bf16 bf16x4v __attribute__((ext_vector_type(4)));
typedef float f32x4 __attribute__((ext_vector_type(4)));
typedef uint32_t u32;
typedef u32 u32x2 __attribute__((ext_vector_type(2)));
typedef u32 u32x4 __attribute__((ext_vector_type(4)));

__device__ __forceinline__ void gld_lds16(const void* g, void* l) {
  __builtin_amdgcn_global_load_lds(
      (const __attribute__((address_space(1))) void*)g,
      (__attribute__((address_space(3))) void*)l, 16, 0, 0);
}

__device__ __forceinline__ f32x4 mfma16(bf16x8 a, bf16x8 b, f32x4 c) {
  return __builtin_amdgcn_mfma_f32_16x16x32_bf16(a, b, c, 0, 0, 0);
}

__device__ __forceinline__ u32 cvtpk_bf16(float lo, float hi) {
  u32 r;
  asm("v_cvt_pk_bf16_f32 %0, %1, %2" : "=v"(r) : "v"(lo), "v"(hi));
  return r;
}

__device__ __forceinline__ float fexp2(float x) {
#if __has_builtin(__builtin_amdgcn_exp2f)
  return __builtin_amdgcn_exp2f(x);
#else
  return exp2f(x);
#endif
}

// ---------------- weight fp32 [K][N] -> bf16 transposed [N][K], 4 weights fused -------
__global__ void wt_cvt4_k(const float* __restrict__ W0, const float* __restrict__ W1,
                          const float* __restrict__ W2, const float* __restrict__ W3,
                          bf16* __restrict__ T0, bf16* __restrict__ T1,
                          bf16* __restrict__ T2, bf16* __restrict__ T3) {
  const float* W = (blockIdx.z == 0) ? W0 : (blockIdx.z == 1) ? W1
                  : (blockIdx.z == 2) ? W2 : W3;
  bf16* WT = (blockIdx.z == 0) ? T0 : (blockIdx.z == 1) ? T1
            : (blockIdx.z == 2) ? T2 : T3;
  __shared__ float t[32][33];
  int tx = threadIdx.x, ty = threadIdx.y;  // 32 x 8
  int bx = blockIdx.x * 32, by = blockIdx.y * 32;
#pragma unroll
  for (int j = 0; j < 32; j += 8)
    t[ty + j][tx] = W[(size_t)(by + ty + j) * 1024 + bx + tx];
  __syncthreads();
#pragma unroll
  for (int j = 0; j < 32; j += 8)
    WT[(size_t)(bx + ty + j) * 1024 + by + tx] = (bf16)t[tx][ty + j];
}

// ---------------- FUSED QKV projection GEMM v3: B direct global->reg, A-only LDS --------
// blockIdx.y selects: 0=Q (qscale), 1=K, 2=V (VT layout out).
// Occupancy fix: B (2MB weight panel, L2-resident) is read straight into VGPR fragments
// — removes 32 KB LDS (now 32 KB total -> 4 blocks/CU) AND the 16-way-conflict linear
// B ds_reads (r21's 9.4M conflict cycles). A-path keeps r19's 1-deep async split.
__global__ __launch_bounds__(256, 4) void gemmf_k(
    const float* __restrict__ Aq, const float* __restrict__ Ak, const float* __restrict__ Av,
    const bf16* __restrict__ WTq, const bf16* __restrict__ WTk, const bf16* __restrict__ WTv,
    const float* __restrict__ bq, const float* __restrict__ bk, const float* __restrict__ bv,
    bf16* __restrict__ Qa, bf16* __restrict__ Ka, bf16* __restrict__ VTa, float qscale) {
  constexpr int K = 1024, BM = 128, BK = 64;
  constexpr int NT = K / BK;  // 16
  __shared__ char lds[2][BM * BK * 2];  // A tiles only: 32 KiB
  const int lane = threadIdx.x & 63, w = threadIdx.x >> 6;
  const int y = blockIdx.y;
  const float* A   = (y == 0) ? Aq : (y == 1) ? Ak : Av;
  const bf16* WT   = (y == 0) ? WTq : (y == 1) ? WTk : WTv;
  const float* bias = (y == 0) ? bq : (y == 1) ? bk : bv;
  const float scale = (y == 0) ? qscale : 1.0f;
  const int nwg = gridDim.x;
  int bid = (int)blockIdx.x;
  bid = (bid & 7) * (nwg >> 3) + (bid >> 3);  // XCD swizzle (512 % 8 == 0)
  const int bn = bid & 7;
  const int bm = bid >> 3;
  const int wm = (w & 1) * 64, wn = (w >> 1) * 64;
  const int q15 = lane & 15, g4 = lane >> 4;
  const int l7 = lane & 7, sl = lane >> 3;
  const int sw = l7 ^ sl;  // A-write swizzled chunk (row&7 == sl)

  const char* gA = (const char*)(A + (size_t)bm * BM * K);  // fp32: row stride 4096 B
  // B fragment base for this wave: rows bn*128 + wn + ni*16 + q15, k = kt*64 + (c*4+g4)*8
  const bf16* gBw = WT + (size_t)(bn * 128 + wn + q15) * K;

  auto stage_loadA = [&](int kt, f32x4 (&a0)[4], f32x4 (&a1)[4]) {
#pragma unroll
    for (int i = 0; i < 4; ++i) {
      int row = w * 32 + i * 8 + sl;
      const char* src = gA + (size_t)row * 4096 + (size_t)kt * 256 + (size_t)l7 * 32;
      a0[i] = *(const f32x4*)src;
      a1[i] = *(const f32x4*)(src + 16);
    }
  };
  auto stage_writeA = [&](int buf, f32x4 (&a0)[4], f32x4 (&a1)[4]) {
    char* lA = lds[buf];
#pragma unroll
    for (int i = 0; i < 4; ++i) {
      int row = w * 32 + i * 8 + sl;
      u32x4 pk;
      pk[0] = cvtpk_bf16(a0[i][0], a0[i][1]);
      pk[1] = cvtpk_bf16(a0[i][2], a0[i][3]);
      pk[2] = cvtpk_bf16(a1[i][0], a1[i][1]);
      pk[3] = cvtpk_bf16(a1[i][2], a1[i][3]);
      *(bf16x8*)(lA + row * 128 + sw * 16) = __builtin_bit_cast(bf16x8, pk);
    }
  };

  f32x4 a0[4], a1[4];
  // prologue: tile 0 staged synchronously
  stage_loadA(0, a0, a1);
  stage_writeA(0, a0, a1);

  f32x4 acc[4][4] = {};
  for (int kt = 0; kt < NT; ++kt) {
    __syncthreads();  // tile kt's A visible; prev tile consumed
    if (kt + 1 < NT) stage_loadA(kt + 1, a0, a1);  // fp32 loads in flight over compute
    // B-frags direct from global (L2-resident weights; no LDS round-trip)
    bf16x8 bfr[4][2];
#pragma unroll
    for (int ni = 0; ni < 4; ++ni)
#pragma unroll
      for (int c = 0; c < 2; ++c)
        bfr[ni][c] = *(const bf16x8*)(gBw + (size_t)ni * 16 * K + kt * 64 + (c * 4 + g4) * 8);
    const char* lA = lds[kt & 1];
    bf16x8 af[4][2];
#pragma unroll
    for (int mi = 0; mi < 4; ++mi)
#pragma unroll
      for (int c = 0; c < 2; ++c) {
        int row = wm + mi * 16 + q15;
        int ch = (c * 4 + g4) ^ (lane & 7);  // inverse of the staging swizzle
        af[mi][c] = *(const bf16x8*)(lA + row * 128 + ch * 16);
      }
#pragma unroll
    for (int mi = 0; mi < 4; ++mi)
#pragma unroll
      for (int ni = 0; ni < 4; ++ni) {
        acc[mi][ni] = mfma16(af[mi][0], bfr[ni][0], acc[mi][ni]);
        acc[mi][ni] = mfma16(af[mi][1], bfr[ni][1], acc[mi][ni]);
      }
    if (kt + 1 < NT) stage_writeA((kt + 1) & 1, a0, a1);  // cvt+write after compute
  }

#pragma unroll
  for (int ni = 0; ni < 4; ++ni) {
    int col = bn * 128 + wn + ni * 16 + q15;
    float bv2 = bias[col];
    int h = col >> 6, dh = col & 63;
    if (y != 2) {
      bf16* out = (y == 0) ? Qa : Ka;
#pragma unroll
      for (int mi = 0; mi < 4; ++mi)
#pragma unroll
        for (int r = 0; r < 4; ++r) {
          int row = bm * BM + wm + mi * 16 + g4 * 4 + r;
          int b = row >> 11, li = row & 2047;
          out[(((size_t)(b * 16 + h) * 2048 + li) << 6) + dh] =
              (bf16)((acc[mi][ni][r] + bv2) * scale);
        }
    } else {
      bf16* out = VTa;  // VT[bh][dh][L]
#pragma unroll
      for (int mi = 0; mi < 4; ++mi)
#pragma unroll
        for (int r = 0; r < 4; ++r) {
          int row = bm * BM + wm + mi * 16 + g4 * 4 + r;
          int b = row >> 11, li = row & 2047;
          out[(((size_t)(b * 16 + h) * 64 + dh) << 11) + li] =
              (bf16)(acc[mi][ni][r] + bv2);
        }
    }
  }
}

// ---------------- out-projection GEMM (bf16 A via gld_lds16, fp32 out) ----------------
__global__ __launch_bounds__(256, 2) void gemm_out_k(
    const bf16* __restrict__ A, const bf16* __restrict__ WT,
    const float* __restrict__ bias, float* __restrict__ Cout) {
  constexpr int K = 1024, N = 1024, BM = 128, BK = 64;
  constexpr int NT = K / BK;  // 16
  __shared__ char lds[2][2][BM * BK * 2];
  const int lane = threadIdx.x & 63, w = threadIdx.x >> 6;
  const int nwg = gridDim.x;
  int bid = (int)blockIdx.x;
  bid = (bid & 7) * (nwg >> 3) + (bid >> 3);
  const int bn = bid & 7;
  const int bm = bid >> 3;
  const int wm = (w & 1) * 64, wn = (w >> 1) * 64;

  const char* gA = (const char*)(A + (size_t)bm * BM * K);
  const char* gB = (const char*)(WT + (size_t)bn * BM * K);

  auto stage = [&](int buf, int kt) {
    char* lA = lds[buf][0];
    char* lB = lds[buf][1];
#pragma unroll
    for (int i = 0; i < 4; ++i) {
      int row = w * 32 + i * 8 + (lane >> 3);
      size_t rb = (size_t)row * (K * 2) + (size_t)kt * (BK * 2) + (size_t)(lane & 7) * 16;
      gld_lds16(gA + rb, lA + (w * 32 + i * 8) * 128);
      gld_lds16(gB + rb, lB + (w * 32 + i * 8) * 128);
    }
  };

  f32x4 acc[4][4] = {};
  stage(0, 0);
  for (int kt = 0; kt < NT; ++kt) {
    __syncthreads();
    if (kt + 1 < NT) stage((kt + 1) & 1, kt + 1);
    const char* lA = lds[kt & 1][0];
    const char* lB = lds[kt & 1][1];
    bf16x8 af[4][2], bfr[4][2];
#pragma unroll
    for (int mi = 0; mi < 4; ++mi)
#pragma unroll
      for (int c = 0; c < 2; ++c) {
        int row = wm + mi * 16 + (lane & 15);
        int ch = c * 4 + (lane >> 4);
        af[mi][c] = *(const bf16x8*)(lA + row * 128 + ch * 16);
      }
#pragma unroll
    for (int ni = 0; ni < 4; ++ni)
#pragma unroll
      for (int c = 0; c < 2; ++c) {
        int row = wn + ni * 16 + (lane & 15);
        int ch = c * 4 + (lane >> 4);
        bfr[ni][c] = *(const bf16x8*)(lB + row * 128 + ch * 16);
      }
#pragma unroll
    for (int mi = 0; mi < 4; ++mi)
#pragma unroll
      for (int ni = 0; ni < 4; ++ni) {
        acc[mi][ni] = mfma16(af[mi][0], bfr[ni][0], acc[mi][ni]);
        acc[mi][ni] = mfma16(af[mi][1], bfr[ni][1], acc[mi][ni]);
      }
  }

#pragma unroll
  for (int ni = 0; ni < 4; ++ni) {
    int col = bn * 128 + wn + ni * 16 + (lane & 15);
    float bv = bias[col];
#pragma unroll
    for (int mi = 0; mi < 4; ++mi)
#pragma unroll
      for (int r = 0; r < 4; ++r) {
        int row = bm * BM + wm + mi * 16 + (lane >> 4) * 4 + r;
        Cout[(size_t)row * N + col] = acc[mi][ni][r] + bv;
      }
  }
}

// ---------------- MFMA flash attention v7 (r17, unchanged, passing) ----------------
__global__ __launch_bounds__(256, 3) void attn_mfma_k(
    const bf16* __restrict__ Q, const bf16* __restrict__ Kg,
    const bf16* __restrict__ VT, bf16* __restrict__ AO) {
  constexpr int L = 2048, DH = 64, NT = L / 64;
  __shared__ char ldsK[2][8192];
  __shared__ char ldsVT[2][8192];
  __shared__ char ldsP[4][2][2048];
  const int lane = threadIdx.x & 63, w = threadIdx.x >> 6;
  const int nwg = gridDim.x;
  int bid = (int)blockIdx.x;
  bid = (bid & 7) * (nwg >> 3) + (bid >> 3);
  const int bh = bid >> 4;
  const int q0 = (bid & 15) * 128;
  const int b = bh >> 4, h = bh & 15;
  const int l7 = lane & 7;
  const int q15 = lane & 15, g4 = lane >> 4;
  const int sl = lane >> 3;
  const int sw = l7 ^ sl;

  const bf16* Qbase = Q + ((size_t)bh * L + q0 + w * 32) * DH;
  bf16x8 qf[2][2];
#pragma unroll
  for (int rt = 0; rt < 2; ++rt)
#pragma unroll
    for (int c = 0; c < 2; ++c)
      qf[rt][c] = *(const bf16x8*)(Qbase + (size_t)(rt * 16 + q15) * DH +
                                   (c * 4 + g4) * 8);

  const char* Kp  = (const char*)(Kg + (size_t)bh * L * DH);
  const char* VTp = (const char*)(VT + (size_t)bh * DH * L);

  auto stage = [&](int buf, int kt) {
#pragma unroll
    for (int c = 0; c < 2; ++c) {
      int chunk = w * 2 + c;
      int row = chunk * 8 + sl;
      gld_lds16(Kp + (size_t)kt * 8192 + (size_t)row * 128 + sw * 16,
                ldsK[buf] + chunk * 1024);
      gld_lds16(VTp + (size_t)row * 4096 + (size_t)kt * 128 + sw * 16,
                ldsVT[buf] + chunk * 1024);
    }
  };

  f32x4 o[2][4] = {};
  float lpart[2] = {0.f, 0.f};

  stage(0, 0);
  for (int kt = 0; kt < NT; ++kt) {
    __syncthreads();
    if (kt + 1 < NT) stage((kt + 1) & 1, kt + 1);
    const char* lK  = ldsK[kt & 1];
    const char* lVT = ldsVT[kt & 1];

    bf16x8 kf[4][2];
#pragma unroll
    for (int sub = 0; sub < 4; ++sub)
#pragma unroll
      for (int c = 0; c < 2; ++c) {
        int key = sub * 16 + q15;
        int ch = (c * 4 + g4) ^ l7;
        kf[sub][c] = *(const bf16x8*)(lK + key * 128 + ch * 16);
      }

#pragma unroll
    for (int rt = 0; rt < 2; ++rt) {
      f32x4 s[4];
#pragma unroll
      for (int sub = 0; sub < 4; ++sub) {
        f32x4 acc = {};
        acc = mfma16(kf[sub][0], qf[rt][0], acc);
        acc = mfma16(kf[sub][1], qf[rt][1], acc);
        s[sub] = acc;
      }
#pragma unroll
      for (int sub = 0; sub < 4; ++sub) {
        float p0 = fexp2(s[sub][0]), p1 = fexp2(s[sub][1]);
        float p2 = fexp2(s[sub][2]), p3 = fexp2(s[sub][3]);
        lpart[rt] += (p0 + p1) + (p2 + p3);
        u32x2 pw;
        pw[0] = cvtpk_bf16(p0, p1);
        pw[1] = cvtpk_bf16(p2, p3);
        bf16x4v pv = __builtin_bit_cast(bf16x4v, pw);
        int chs = (2 * sub + (g4 >> 1)) ^ l7;
        *(bf16x4v*)(ldsP[w][rt] + q15 * 128 + chs * 16 + (g4 & 1) * 8) = pv;
      }
    }

    asm volatile("s_waitcnt lgkmcnt(0)" ::: "memory");
    __builtin_amdgcn_sched_barrier(0);

    bf16x8 pf[2][2];
#pragma unroll
    for (int rt = 0; rt < 2; ++rt)
#pragma unroll
      for (int c = 0; c < 2; ++c) {
        int ch = (c * 4 + g4) ^ l7;
        pf[rt][c] = *(const bf16x8*)(ldsP[w][rt] + q15 * 128 + ch * 16);
      }

#pragma unroll
    for (int n = 0; n < 4; ++n) {
      int dim = n * 16 + q15;
      bf16x8 vf[2];
#pragma unroll
      for (int c = 0; c < 2; ++c) {
        int ch = (c * 4 + g4) ^ l7;
        vf[c] = *(const bf16x8*)(lVT + dim * 128 + ch * 16);
      }
#pragma unroll
      for (int rt = 0; rt < 2; ++rt) {
        o[rt][n] = mfma16(pf[rt][0], vf[0], o[rt][n]);
        o[rt][n] = mfma16(pf[rt][1], vf[1], o[rt][n]);
      }
    }
  }

  float lf[2];
#pragma unroll
  for (int rt = 0; rt < 2; ++rt) {
    float v = lpart[rt];
    v += __shfl_xor(v, 16, 64);
    v += __shfl_xor(v, 32, 64);
    lf[rt] = v;
  }

#pragma unroll
  for (int rt = 0; rt < 2; ++rt) {
    float inv[4];
#pragma unroll
    for (int r = 0; r < 4; ++r)
      inv[r] = 1.f / __shfl(lf[rt], g4 * 4 + r, 64);
#pragma unroll
    for (int n = 0; n < 4; ++n) {
      int col = h * 64 + n * 16 + q15;
#pragma unroll
      for (int r = 0; r < 4; ++r) {
        int qrow = q0 + w * 32 + rt * 16 + g4 * 4 + r;
        AO[((size_t)b * L + qrow) * 1024 + col] = (bf16)(o[rt][n][r] * inv[r]);
      }
    }
  }
}

// ---------------- launch ----------------
extern "C" void kernel_launch(void* const* d_in, const int* in_sizes, int n_in,
                              void* d_out, int out_size, void* d_ws, size_t ws_size,
                              hipStream_t stream) {
  (void)in_sizes; (void)n_in; (void)out_size;
  const size_t MB = 1u << 20;
  if (ws_size < 73 * MB) return;

  const float* q  = (const float*)d_in[0];
  const float* k  = (const float*)d_in[1];
  const float* v  = (const float*)d_in[2];
  const float* Wq = (const float*)d_in[3];
  const float* bq = (const float*)d_in[4];
  const float* Wk = (const float*)d_in[5];
  const float* bk = (const float*)d_in[6];
  const float* Wv = (const float*)d_in[7];
  const float* bv = (const float*)d_in[8];
  const float* Wo = (const float*)d_in[9];
  const float* bo = (const float*)d_in[10];

  char* ws = (char*)d_ws;
  bf16* Qa  = (bf16*)(ws + 0 * MB);    // 16 MB
  bf16* Ka  = (bf16*)(ws + 16 * MB);   // 16 MB
  bf16* VTa = (bf16*)(ws + 32 * MB);   // 16 MB
  bf16* AO  = (bf16*)(ws + 48 * MB);   // 16 MB
  bf16* WqT = (bf16*)(ws + 64 * MB);
  bf16* WkT = (bf16*)(ws + 66 * MB);
  bf16* WvT = (bf16*)(ws + 68 * MB);
  bf16* WoT = (bf16*)(ws + 70 * MB);

  dim3 tb(32, 8);
  wt_cvt4_k<<<dim3(32, 32, 4), tb, 0, stream>>>(Wq, Wk, Wv, Wo, WqT, WkT, WvT, WoT);

  // fused fp32->bf16 QKV projections (one dispatch, 512x3 blocks)
  // Q scale folds softmax 1/8 AND 1/ln2 (exp2-based softmax)
  gemmf_k<<<dim3(512, 3), 256, 0, stream>>>(
      q, k, v, WqT, WkT, WvT, bq, bk, bv, Qa, Ka, VTa,
      0.125f * 1.4426950408889634f);

  attn_mfma_k<<<1024, 256, 0, stream>>>(Qa, Ka, VTa, AO);

  gemm_out_k<<<512, 256, 0, stream>>>(AO, WoT, bo, (float*)d_out);
}

// Round 24
// 192.540 us; speedup vs baseline: 1.3552x; 1.3552x over previous
//
#include <hip/hip_runtime.h>
#include <hip/hip_bf16.h>
#include <stdint.h>

typedef __bf16 bf16;
typedef __bf16 bf16x8 __attribute__((ext_vector_type(8)));
typedef __bf16 bf16x4v __attribute__((ext_vector_type(4)));
typedef float f32x4 __attribute__((ext_vector_type(4)));
typedef uint32_t u32;
typedef u32 u32x2 __attribute__((ext_vector_type(2)));
typedef u32 u32x4 __attribute__((ext_vector_type(4)));

__device__ __forceinline__ void gld_lds16(const void* g, void* l) {
  __builtin_amdgcn_global_load_lds(
      (const __attribute__((address_space(1))) void*)g,
      (__attribute__((address_space(3))) void*)l, 16, 0, 0);
}

__device__ __forceinline__ f32x4 mfma16(bf16x8 a, bf16x8 b, f32x4 c) {
  return __builtin_amdgcn_mfma_f32_16x16x32_bf16(a, b, c, 0, 0, 0);
}

__device__ __forceinline__ u32 cvtpk_bf16(float lo, float hi) {
  u32 r;
  asm("v_cvt_pk_bf16_f32 %0, %1, %2" : "=v"(r) : "v"(lo), "v"(hi));
  return r;
}

__device__ __forceinline__ float fexp2(float x) {
#if __has_builtin(__builtin_amdgcn_exp2f)
  return __builtin_amdgcn_exp2f(x);
#else
  return exp2f(x);
#endif
}

// ---------------- weight fp32 [K][N] -> bf16 transposed [N][K], 4 weights fused -------
__global__ void wt_cvt4_k(const float* __restrict__ W0, const float* __restrict__ W1,
                          const float* __restrict__ W2, const float* __restrict__ W3,
                          bf16* __restrict__ T0, bf16* __restrict__ T1,
                          bf16* __restrict__ T2, bf16* __restrict__ T3) {
  const float* W = (blockIdx.z == 0) ? W0 : (blockIdx.z == 1) ? W1
                  : (blockIdx.z == 2) ? W2 : W3;
  bf16* WT = (blockIdx.z == 0) ? T0 : (blockIdx.z == 1) ? T1
            : (blockIdx.z == 2) ? T2 : T3;
  __shared__ float t[32][33];
  int tx = threadIdx.x, ty = threadIdx.y;  // 32 x 8
  int bx = blockIdx.x * 32, by = blockIdx.y * 32;
#pragma unroll
  for (int j = 0; j < 32; j += 8)
    t[ty + j][tx] = W[(size_t)(by + ty + j) * 1024 + bx + tx];
  __syncthreads();
#pragma unroll
  for (int j = 0; j < 32; j += 8)
    WT[(size_t)(bx + ty + j) * 1024 + by + tx] = (bf16)t[tx][ty + j];
}

// ---------------- FUSED QKV projection GEMM (r19-best: B via gld_lds16, 1-deep A split) ---
__global__ __launch_bounds__(256, 2) void gemmf_k(
    const float* __restrict__ Aq, const float* __restrict__ Ak, const float* __restrict__ Av,
    const bf16* __restrict__ WTq, const bf16* __restrict__ WTk, const bf16* __restrict__ WTv,
    const float* __restrict__ bq, const float* __restrict__ bk, const float* __restrict__ bv,
    bf16* __restrict__ Qa, bf16* __restrict__ Ka, bf16* __restrict__ VTa, float qscale) {
  constexpr int K = 1024, BM = 128, BK = 64;
  constexpr int NT = K / BK;  // 16
  __shared__ char lds[2][2][BM * BK * 2];  // 64 KiB
  const int lane = threadIdx.x & 63, w = threadIdx.x >> 6;
  const int y = blockIdx.y;
  const float* A   = (y == 0) ? Aq : (y == 1) ? Ak : Av;
  const bf16* WT   = (y == 0) ? WTq : (y == 1) ? WTk : WTv;
  const float* bias = (y == 0) ? bq : (y == 1) ? bk : bv;
  const float scale = (y == 0) ? qscale : 1.0f;
  const int nwg = gridDim.x;
  int bid = (int)blockIdx.x;
  bid = (bid & 7) * (nwg >> 3) + (bid >> 3);  // XCD swizzle (512 % 8 == 0)
  const int bn = bid & 7;
  const int bm = bid >> 3;
  const int wm = (w & 1) * 64, wn = (w >> 1) * 64;
  const int l7 = lane & 7, sl = lane >> 3;
  const int sw = l7 ^ sl;  // A-write swizzled chunk (row&7 == sl)

  const char* gA = (const char*)(A + (size_t)bm * BM * K);    // fp32: row stride 4096 B
  const char* gB = (const char*)(WT + (size_t)bn * BM * K);   // bf16: row stride 2048 B

  auto stageB = [&](int buf, int kt) {
    char* lB = lds[buf][1];
#pragma unroll
    for (int i = 0; i < 4; ++i) {
      int row = w * 32 + i * 8 + sl;
      gld_lds16(gB + (size_t)row * 2048 + (size_t)kt * 128 + (size_t)l7 * 16,
                lB + (w * 32 + i * 8) * 128);
    }
  };
  auto stage_loadA = [&](int kt, f32x4 (&a0)[4], f32x4 (&a1)[4]) {
#pragma unroll
    for (int i = 0; i < 4; ++i) {
      int row = w * 32 + i * 8 + sl;
      const char* src = gA + (size_t)row * 4096 + (size_t)kt * 256 + (size_t)l7 * 32;
      a0[i] = *(const f32x4*)src;
      a1[i] = *(const f32x4*)(src + 16);
    }
  };
  auto stage_writeA = [&](int buf, f32x4 (&a0)[4], f32x4 (&a1)[4]) {
    char* lA = lds[buf][0];
#pragma unroll
    for (int i = 0; i < 4; ++i) {
      int row = w * 32 + i * 8 + sl;
      u32x4 pk;
      pk[0] = cvtpk_bf16(a0[i][0], a0[i][1]);
      pk[1] = cvtpk_bf16(a0[i][2], a0[i][3]);
      pk[2] = cvtpk_bf16(a1[i][0], a1[i][1]);
      pk[3] = cvtpk_bf16(a1[i][2], a1[i][3]);
      *(bf16x8*)(lA + row * 128 + sw * 16) = __builtin_bit_cast(bf16x8, pk);
    }
  };

  f32x4 a0[4], a1[4];
  stageB(0, 0);
  stage_loadA(0, a0, a1);
  stage_writeA(0, a0, a1);

  f32x4 acc[4][4] = {};
  for (int kt = 0; kt < NT; ++kt) {
    __syncthreads();
    if (kt + 1 < NT) {
      stageB((kt + 1) & 1, kt + 1);
      stage_loadA(kt + 1, a0, a1);
    }
    const char* lA = lds[kt & 1][0];
    const char* lB = lds[kt & 1][1];
    bf16x8 af[4][2], bfr[4][2];
#pragma unroll
    for (int mi = 0; mi < 4; ++mi)
#pragma unroll
      for (int c = 0; c < 2; ++c) {
        int row = wm + mi * 16 + (lane & 15);
        int ch = (c * 4 + (lane >> 4)) ^ (lane & 7);
        af[mi][c] = *(const bf16x8*)(lA + row * 128 + ch * 16);
      }
#pragma unroll
    for (int ni = 0; ni < 4; ++ni)
#pragma unroll
      for (int c = 0; c < 2; ++c) {
        int row = wn + ni * 16 + (lane & 15);
        int ch = c * 4 + (lane >> 4);
        bfr[ni][c] = *(const bf16x8*)(lB + row * 128 + ch * 16);
      }
#pragma unroll
    for (int mi = 0; mi < 4; ++mi)
#pragma unroll
      for (int ni = 0; ni < 4; ++ni) {
        acc[mi][ni] = mfma16(af[mi][0], bfr[ni][0], acc[mi][ni]);
        acc[mi][ni] = mfma16(af[mi][1], bfr[ni][1], acc[mi][ni]);
      }
    if (kt + 1 < NT) stage_writeA((kt + 1) & 1, a0, a1);
  }

#pragma unroll
  for (int ni = 0; ni < 4; ++ni) {
    int col = bn * 128 + wn + ni * 16 + (lane & 15);
    float bv2 = bias[col];
    int h = col >> 6, dh = col & 63;
    if (y != 2) {
      bf16* out = (y == 0) ? Qa : Ka;
#pragma unroll
      for (int mi = 0; mi < 4; ++mi)
#pragma unroll
        for (int r = 0; r < 4; ++r) {
          int row = bm * BM + wm + mi * 16 + (lane >> 4) * 4 + r;
          int b = row >> 11, li = row & 2047;
          out[(((size_t)(b * 16 + h) * 2048 + li) << 6) + dh] =
              (bf16)((acc[mi][ni][r] + bv2) * scale);
        }
    } else {
      bf16* out = VTa;  // VT[bh][dh][L]
#pragma unroll
      for (int mi = 0; mi < 4; ++mi)
#pragma unroll
        for (int r = 0; r < 4; ++r) {
          int row = bm * BM + wm + mi * 16 + (lane >> 4) * 4 + r;
          int b = row >> 11, li = row & 2047;
          out[(((size_t)(b * 16 + h) * 64 + dh) << 11) + li] =
              (bf16)(acc[mi][ni][r] + bv2);
        }
    }
  }
}

// ---------------- out-projection GEMM (bf16 A via gld_lds16, fp32 out) ----------------
__global__ __launch_bounds__(256, 2) void gemm_out_k(
    const bf16* __restrict__ A, const bf16* __restrict__ WT,
    const float* __restrict__ bias, float* __restrict__ Cout) {
  constexpr int K = 1024, N = 1024, BM = 128, BK = 64;
  constexpr int NT = K / BK;  // 16
  __shared__ char lds[2][2][BM * BK * 2];
  const int lane = threadIdx.x & 63, w = threadIdx.x >> 6;
  const int nwg = gridDim.x;
  int bid = (int)blockIdx.x;
  bid = (bid & 7) * (nwg >> 3) + (bid >> 3);
  const int bn = bid & 7;
  const int bm = bid >> 3;
  const int wm = (w & 1) * 64, wn = (w >> 1) * 64;

  const char* gA = (const char*)(A + (size_t)bm * BM * K);
  const char* gB = (const char*)(WT + (size_t)bn * BM * K);

  auto stage = [&](int buf, int kt) {
    char* lA = lds[buf][0];
    char* lB = lds[buf][1];
#pragma unroll
    for (int i = 0; i < 4; ++i) {
      int row = w * 32 + i * 8 + (lane >> 3);
      size_t rb = (size_t)row * (K * 2) + (size_t)kt * (BK * 2) + (size_t)(lane & 7) * 16;
      gld_lds16(gA + rb, lA + (w * 32 + i * 8) * 128);
      gld_lds16(gB + rb, lB + (w * 32 + i * 8) * 128);
    }
  };

  f32x4 acc[4][4] = {};
  stage(0, 0);
  for (int kt = 0; kt < NT; ++kt) {
    __syncthreads();
    if (kt + 1 < NT) stage((kt + 1) & 1, kt + 1);
    const char* lA = lds[kt & 1][0];
    const char* lB = lds[kt & 1][1];
    bf16x8 af[4][2], bfr[4][2];
#pragma unroll
    for (int mi = 0; mi < 4; ++mi)
#pragma unroll
      for (int c = 0; c < 2; ++c) {
        int row = wm + mi * 16 + (lane & 15);
        int ch = c * 4 + (lane >> 4);
        af[mi][c] = *(const bf16x8*)(lA + row * 128 + ch * 16);
      }
#pragma unroll
    for (int ni = 0; ni < 4; ++ni)
#pragma unroll
      for (int c = 0; c < 2; ++c) {
        int row = wn + ni * 16 + (lane & 15);
        int ch = c * 4 + (lane >> 4);
        bfr[ni][c] = *(const bf16x8*)(lB + row * 128 + ch * 16);
      }
#pragma unroll
    for (int mi = 0; mi < 4; ++mi)
#pragma unroll
      for (int ni = 0; ni < 4; ++ni) {
        acc[mi][ni] = mfma16(af[mi][0], bfr[ni][0], acc[mi][ni]);
        acc[mi][ni] = mfma16(af[mi][1], bfr[ni][1], acc[mi][ni]);
      }
  }

#pragma unroll
  for (int ni = 0; ni < 4; ++ni) {
    int col = bn * 128 + wn + ni * 16 + (lane & 15);
    float bv = bias[col];
#pragma unroll
    for (int mi = 0; mi < 4; ++mi)
#pragma unroll
      for (int r = 0; r < 4; ++r) {
        int row = bm * BM + wm + mi * 16 + (lane >> 4) * 4 + r;
        Cout[(size_t)row * N + col] = acc[mi][ni][r] + bv;
      }
  }
}

// ---------------- MFMA flash attention v8b: K single-buffer + pre-barrier load drain ----
// r23's 1.86e-3 failure: a wave can cross __syncthreads with kf ds_reads still queued
// (backend's pre-barrier waitcnt covers STORES for visibility, not loads); another wave's
// stageK DMA then overwrites ldsK under the in-flight read. Fix: explicit lgkmcnt(0) +
// sched_barrier(0) BEFORE the mid barrier — kf architecturally complete first.
__global__ __launch_bounds__(256, 4) void attn_mfma_k(
    const bf16* __restrict__ Q, const bf16* __restrict__ Kg,
    const bf16* __restrict__ VT, bf16* __restrict__ AO) {
  constexpr int L = 2048, DH = 64, NT = L / 64;
  __shared__ char ldsK[8192];       // K tile, single-buffered
  __shared__ char ldsVT[2][8192];   // VT tiles, double-buffered
  __shared__ char ldsP[4][2][2048];
  const int lane = threadIdx.x & 63, w = threadIdx.x >> 6;
  const int nwg = gridDim.x;
  int bid = (int)blockIdx.x;
  bid = (bid & 7) * (nwg >> 3) + (bid >> 3);  // XCD swizzle
  const int bh = bid >> 4;
  const int q0 = (bid & 15) * 128;
  const int b = bh >> 4, h = bh & 15;
  const int l7 = lane & 7;
  const int q15 = lane & 15, g4 = lane >> 4;
  const int sl = lane >> 3;
  const int sw = l7 ^ sl;

  const bf16* Qbase = Q + ((size_t)bh * L + q0 + w * 32) * DH;
  bf16x8 qf[2][2];
#pragma unroll
  for (int rt = 0; rt < 2; ++rt)
#pragma unroll
    for (int c = 0; c < 2; ++c)
      qf[rt][c] = *(const bf16x8*)(Qbase + (size_t)(rt * 16 + q15) * DH +
                                   (c * 4 + g4) * 8);

  const char* Kp  = (const char*)(Kg + (size_t)bh * L * DH);
  const char* VTp = (const char*)(VT + (size_t)bh * DH * L);

  auto stageK = [&](int kt) {
#pragma unroll
    for (int c = 0; c < 2; ++c) {
      int chunk = w * 2 + c;
      int row = chunk * 8 + sl;
      gld_lds16(Kp + (size_t)kt * 8192 + (size_t)row * 128 + sw * 16,
                ldsK + chunk * 1024);
    }
  };
  auto stageVT = [&](int buf, int kt) {
#pragma unroll
    for (int c = 0; c < 2; ++c) {
      int chunk = w * 2 + c;
      int row = chunk * 8 + sl;
      gld_lds16(VTp + (size_t)row * 4096 + (size_t)kt * 128 + sw * 16,
                ldsVT[buf] + chunk * 1024);
    }
  };

  f32x4 o[2][4] = {};
  float lpart[2] = {0.f, 0.f};

  stageK(0);
  stageVT(0, 0);
  for (int kt = 0; kt < NT; ++kt) {
    __syncthreads();  // K(kt)+VT(kt) staged & visible; prev VT consumed
    const char* lVT = ldsVT[kt & 1];

    // --- K fragments into registers (conflict-free b128) ---
    bf16x8 kf[4][2];
#pragma unroll
    for (int sub = 0; sub < 4; ++sub)
#pragma unroll
      for (int c = 0; c < 2; ++c) {
        int key = sub * 16 + q15;
        int ch = (c * 4 + g4) ^ l7;
        kf[sub][c] = *(const bf16x8*)(ldsK + key * 128 + ch * 16);
      }
    // drain in-flight kf reads BEFORE the barrier (load-vs-remote-DMA hazard)
    asm volatile("s_waitcnt lgkmcnt(0)" ::: "memory");
    __builtin_amdgcn_sched_barrier(0);
    __syncthreads();  // all waves' kf reads architecturally complete -> ldsK reusable
    if (kt + 1 < NT) {
      stageK(kt + 1);
      stageVT((kt + 1) & 1, kt + 1);
    }

    // --- phase 1: both row-tiles' S^T + exp2 + P stores (disjoint buffers) ---
#pragma unroll
    for (int rt = 0; rt < 2; ++rt) {
      f32x4 s[4];
#pragma unroll
      for (int sub = 0; sub < 4; ++sub) {
        f32x4 acc = {};
        acc = mfma16(kf[sub][0], qf[rt][0], acc);
        acc = mfma16(kf[sub][1], qf[rt][1], acc);
        s[sub] = acc;
      }
#pragma unroll
      for (int sub = 0; sub < 4; ++sub) {
        float p0 = fexp2(s[sub][0]), p1 = fexp2(s[sub][1]);
        float p2 = fexp2(s[sub][2]), p3 = fexp2(s[sub][3]);
        lpart[rt] += (p0 + p1) + (p2 + p3);
        u32x2 pw;
        pw[0] = cvtpk_bf16(p0, p1);
        pw[1] = cvtpk_bf16(p2, p3);
        bf16x4v pv = __builtin_bit_cast(bf16x4v, pw);
        int chs = (2 * sub + (g4 >> 1)) ^ l7;
        *(bf16x4v*)(ldsP[w][rt] + q15 * 128 + chs * 16 + (g4 & 1) * 8) = pv;
      }
    }

    // --- ONE ordering point per kt (rule 18: hard wait + sched_barrier) ---
    asm volatile("s_waitcnt lgkmcnt(0)" ::: "memory");
    __builtin_amdgcn_sched_barrier(0);

    // --- phase 2: P fragment readback (both rt) ---
    bf16x8 pf[2][2];
#pragma unroll
    for (int rt = 0; rt < 2; ++rt)
#pragma unroll
      for (int c = 0; c < 2; ++c) {
        int ch = (c * 4 + g4) ^ l7;
        pf[rt][c] = *(const bf16x8*)(ldsP[w][rt] + q15 * 128 + ch * 16);
      }

    // --- PV: hoisted VT fragments, 2 mfma per (n, rt) ---
#pragma unroll
    for (int n = 0; n < 4; ++n) {
      int dim = n * 16 + q15;
      bf16x8 vf[2];
#pragma unroll
      for (int c = 0; c < 2; ++c) {
        int ch = (c * 4 + g4) ^ l7;
        vf[c] = *(const bf16x8*)(lVT + dim * 128 + ch * 16);
      }
#pragma unroll
      for (int rt = 0; rt < 2; ++rt) {
        o[rt][n] = mfma16(pf[rt][0], vf[0], o[rt][n]);
        o[rt][n] = mfma16(pf[rt][1], vf[1], o[rt][n]);
      }
    }
  }

  // --- final l: reduce over the 4 g-groups of each qrow (2 shfl rounds) ---
  float lf[2];
#pragma unroll
  for (int rt = 0; rt < 2; ++rt) {
    float v = lpart[rt];
    v += __shfl_xor(v, 16, 64);
    v += __shfl_xor(v, 32, 64);
    lf[rt] = v;
  }

  // --- epilogue: redistribute l to D-layout rows, write AO [B,L,1024] ---
#pragma unroll
  for (int rt = 0; rt < 2; ++rt) {
    float inv[4];
#pragma unroll
    for (int r = 0; r < 4; ++r)
      inv[r] = 1.f / __shfl(lf[rt], g4 * 4 + r, 64);
#pragma unroll
    for (int n = 0; n < 4; ++n) {
      int col = h * 64 + n * 16 + q15;
#pragma unroll
      for (int r = 0; r < 4; ++r) {
        int qrow = q0 + w * 32 + rt * 16 + g4 * 4 + r;
        AO[((size_t)b * L + qrow) * 1024 + col] = (bf16)(o[rt][n][r] * inv[r]);
      }
    }
  }
}

// ---------------- launch ----------------
extern "C" void kernel_launch(void* const* d_in, const int* in_sizes, int n_in,
                              void* d_out, int out_size, void* d_ws, size_t ws_size,
                              hipStream_t stream) {
  (void)in_sizes; (void)n_in; (void)out_size;
  const size_t MB = 1u << 20;
  if (ws_size < 73 * MB) return;

  const float* q  = (const float*)d_in[0];
  const float* k  = (const float*)d_in[1];
  const float* v  = (const float*)d_in[2];
  const float* Wq = (const float*)d_in[3];
  const float* bq = (const float*)d_in[4];
  const float* Wk = (const float*)d_in[5];
  const float* bk = (const float*)d_in[6];
  const float* Wv = (const float*)d_in[7];
  const float* bv = (const float*)d_in[8];
  const float* Wo = (const float*)d_in[9];
  const float* bo = (const float*)d_in[10];

  char* ws = (char*)d_ws;
  bf16* Qa  = (bf16*)(ws + 0 * MB);    // 16 MB
  bf16* Ka  = (bf16*)(ws + 16 * MB);   // 16 MB
  bf16* VTa = (bf16*)(ws + 32 * MB);   // 16 MB
  bf16* AO  = (bf16*)(ws + 48 * MB);   // 16 MB
  bf16* WqT = (bf16*)(ws + 64 * MB);
  bf16* WkT = (bf16*)(ws + 66 * MB);
  bf16* WvT = (bf16*)(ws + 68 * MB);
  bf16* WoT = (bf16*)(ws + 70 * MB);

  dim3 tb(32, 8);
  wt_cvt4_k<<<dim3(32, 32, 4), tb, 0, stream>>>(Wq, Wk, Wv, Wo, WqT, WkT, WvT, WoT);

  // fused fp32->bf16 QKV projections; Q scale folds softmax 1/8 AND 1/ln2
  gemmf_k<<<dim3(512, 3), 256, 0, stream>>>(
      q, k, v, WqT, WkT, WvT, bq, bk, bv, Qa, Ka, VTa,
      0.125f * 1.4426950408889634f);

  attn_mfma_k<<<1024, 256, 0, stream>>>(Qa, Ka, VTa, AO);

  gemm_out_k<<<512, 256, 0, stream>>>(AO, WoT, bo, (float*)d_out);
}